// Round 1
// baseline (588.608 us; speedup 1.0000x reference)
//
#include <hip/hip_runtime.h>

#define N_NODES 50000
#define N_EDGES 800000

__device__ __forceinline__ float lane_bcast(float v, int l) {
    return __builtin_bit_cast(float, __builtin_amdgcn_readlane(__builtin_bit_cast(int, v), l));
}

// ---------------------------------------------------------------------------
// Edge kernel: for each edge e, msg = relu(x[src] + ea@linW + linB),
// atomicAdd into agg[dst]. One edge per wave; lane = output channel (0..63).
// linW column for this lane lives in 32 VGPRs; ea broadcast via v_readlane.
// ---------------------------------------------------------------------------
__global__ __launch_bounds__(256) void gine_edge(
    const float* __restrict__ xin,   // [N,64]
    const float* __restrict__ ea,    // [E,32]
    const int*   __restrict__ srcp,  // [E]
    const int*   __restrict__ dstp,  // [E]
    const float* __restrict__ linW,  // [32,64]
    const float* __restrict__ linB,  // [64]
    float*       __restrict__ agg)   // [N,64]
{
    const int lane   = threadIdx.x & 63;
    const int gwave  = (blockIdx.x * blockDim.x + threadIdx.x) >> 6;
    const int nwaves = (gridDim.x * blockDim.x) >> 6;

    float w[32];
#pragma unroll
    for (int k = 0; k < 32; ++k) w[k] = linW[k * 64 + lane];
    const float bias = linB[lane];

    for (int e = gwave; e < N_EDGES; e += nwaves) {
        const int s = srcp[e];
        const int d = dstp[e];
        const float eav = ea[e * 32 + (lane & 31)];   // lanes 0-31 / 32-63 dup
        float m0 = xin[s * 64 + lane] + bias;
        float m1 = 0.f, m2 = 0.f, m3 = 0.f;
#pragma unroll
        for (int k = 0; k < 32; k += 4) {
            m0 = fmaf(lane_bcast(eav, k + 0), w[k + 0], m0);
            m1 = fmaf(lane_bcast(eav, k + 1), w[k + 1], m1);
            m2 = fmaf(lane_bcast(eav, k + 2), w[k + 2], m2);
            m3 = fmaf(lane_bcast(eav, k + 3), w[k + 3], m3);
        }
        const float m = fmaxf((m0 + m1) + (m2 + m3), 0.0f);
        atomicAdd(&agg[d * 64 + lane], m);
    }
}

// ---------------------------------------------------------------------------
// Node kernel (conv1): h = x + agg; h = relu(h@w1+b1); h = relu(h@w2+b2).
// One node per wave; lane = channel. Weight columns in VGPRs (128 regs).
// ---------------------------------------------------------------------------
__global__ __launch_bounds__(256) void gine_node(
    const float* __restrict__ xin,   // [N,64]
    const float* __restrict__ agg,   // [N,64]
    const float* __restrict__ w1,    // [64,64]
    const float* __restrict__ b1,    // [64]
    const float* __restrict__ w2,    // [64,64]
    const float* __restrict__ b2,    // [64]
    float*       __restrict__ hout)  // [N,64]
{
    const int lane   = threadIdx.x & 63;
    const int gwave  = (blockIdx.x * blockDim.x + threadIdx.x) >> 6;
    const int nwaves = (gridDim.x * blockDim.x) >> 6;

    float w1c[64], w2c[64];
#pragma unroll
    for (int k = 0; k < 64; ++k) w1c[k] = w1[k * 64 + lane];
#pragma unroll
    for (int k = 0; k < 64; ++k) w2c[k] = w2[k * 64 + lane];
    const float bb1 = b1[lane], bb2 = b2[lane];

    for (int n = gwave; n < N_NODES; n += nwaves) {
        const float h = xin[n * 64 + lane] + agg[n * 64 + lane];

        float t0 = bb1, t1 = 0.f, t2 = 0.f, t3 = 0.f;
#pragma unroll
        for (int k = 0; k < 64; k += 4) {
            t0 = fmaf(lane_bcast(h, k + 0), w1c[k + 0], t0);
            t1 = fmaf(lane_bcast(h, k + 1), w1c[k + 1], t1);
            t2 = fmaf(lane_bcast(h, k + 2), w1c[k + 2], t2);
            t3 = fmaf(lane_bcast(h, k + 3), w1c[k + 3], t3);
        }
        const float t = fmaxf((t0 + t1) + (t2 + t3), 0.0f);

        float u0 = bb2, u1 = 0.f, u2 = 0.f, u3 = 0.f;
#pragma unroll
        for (int k = 0; k < 64; k += 4) {
            u0 = fmaf(lane_bcast(t, k + 0), w2c[k + 0], u0);
            u1 = fmaf(lane_bcast(t, k + 1), w2c[k + 1], u1);
            u2 = fmaf(lane_bcast(t, k + 2), w2c[k + 2], u2);
            u3 = fmaf(lane_bcast(t, k + 3), w2c[k + 3], u3);
        }
        const float u = fmaxf((u0 + u1) + (u2 + u3), 0.0f);

        hout[n * 64 + lane] = u;
    }
}

// ---------------------------------------------------------------------------
// Node kernel (conv2 + head): h2 = MLP(h1 + agg); out = h2@head_w + head_b.
// head: lanes 0..31 produce the 32 output channels.
// ---------------------------------------------------------------------------
__global__ __launch_bounds__(256) void gine_node_head(
    const float* __restrict__ xin,   // [N,64]  (h1)
    const float* __restrict__ agg,   // [N,64]
    const float* __restrict__ w1,    // [64,64]
    const float* __restrict__ b1,    // [64]
    const float* __restrict__ w2,    // [64,64]
    const float* __restrict__ b2,    // [64]
    const float* __restrict__ hw,    // [64,32]
    const float* __restrict__ hb,    // [32]
    float*       __restrict__ outp)  // [N,32]
{
    const int lane   = threadIdx.x & 63;
    const int gwave  = (blockIdx.x * blockDim.x + threadIdx.x) >> 6;
    const int nwaves = (gridDim.x * blockDim.x) >> 6;

    float w1c[64], w2c[64], hwc[64];
#pragma unroll
    for (int k = 0; k < 64; ++k) w1c[k] = w1[k * 64 + lane];
#pragma unroll
    for (int k = 0; k < 64; ++k) w2c[k] = w2[k * 64 + lane];
#pragma unroll
    for (int k = 0; k < 64; ++k) hwc[k] = hw[k * 32 + (lane & 31)];
    const float bb1 = b1[lane], bb2 = b2[lane];
    const float hbb = hb[lane & 31];

    for (int n = gwave; n < N_NODES; n += nwaves) {
        const float h = xin[n * 64 + lane] + agg[n * 64 + lane];

        float t0 = bb1, t1 = 0.f, t2 = 0.f, t3 = 0.f;
#pragma unroll
        for (int k = 0; k < 64; k += 4) {
            t0 = fmaf(lane_bcast(h, k + 0), w1c[k + 0], t0);
            t1 = fmaf(lane_bcast(h, k + 1), w1c[k + 1], t1);
            t2 = fmaf(lane_bcast(h, k + 2), w1c[k + 2], t2);
            t3 = fmaf(lane_bcast(h, k + 3), w1c[k + 3], t3);
        }
        const float t = fmaxf((t0 + t1) + (t2 + t3), 0.0f);

        float u0 = bb2, u1 = 0.f, u2 = 0.f, u3 = 0.f;
#pragma unroll
        for (int k = 0; k < 64; k += 4) {
            u0 = fmaf(lane_bcast(t, k + 0), w2c[k + 0], u0);
            u1 = fmaf(lane_bcast(t, k + 1), w2c[k + 1], u1);
            u2 = fmaf(lane_bcast(t, k + 2), w2c[k + 2], u2);
            u3 = fmaf(lane_bcast(t, k + 3), w2c[k + 3], u3);
        }
        const float u = fmaxf((u0 + u1) + (u2 + u3), 0.0f);

        // head: out[n, c] = sum_k h2[k] * head_w[k, c] + head_b[c], c = lane<32
        float o0 = hbb, o1 = 0.f, o2 = 0.f, o3 = 0.f;
#pragma unroll
        for (int k = 0; k < 64; k += 4) {
            o0 = fmaf(lane_bcast(u, k + 0), hwc[k + 0], o0);
            o1 = fmaf(lane_bcast(u, k + 1), hwc[k + 1], o1);
            o2 = fmaf(lane_bcast(u, k + 2), hwc[k + 2], o2);
            o3 = fmaf(lane_bcast(u, k + 3), hwc[k + 3], o3);
        }
        if (lane < 32) outp[n * 32 + lane] = (o0 + o1) + (o2 + o3);
    }
}

extern "C" void kernel_launch(void* const* d_in, const int* in_sizes, int n_in,
                              void* d_out, int out_size, void* d_ws, size_t ws_size,
                              hipStream_t stream) {
    const float* x     = (const float*)d_in[0];
    const float* ea    = (const float*)d_in[1];
    const int*   ei    = (const int*)  d_in[2];
    const float* c1lw  = (const float*)d_in[3];
    const float* c1lb  = (const float*)d_in[4];
    const float* c1w1  = (const float*)d_in[5];
    const float* c1b1  = (const float*)d_in[6];
    const float* c1w2  = (const float*)d_in[7];
    const float* c1b2  = (const float*)d_in[8];
    const float* c2lw  = (const float*)d_in[9];
    const float* c2lb  = (const float*)d_in[10];
    const float* c2w1  = (const float*)d_in[11];
    const float* c2b1  = (const float*)d_in[12];
    const float* c2w2  = (const float*)d_in[13];
    const float* c2b2  = (const float*)d_in[14];
    const float* hw    = (const float*)d_in[15];
    const float* hb    = (const float*)d_in[16];

    const int* srcp = ei;
    const int* dstp = ei + N_EDGES;

    float* agg = (float*)d_ws;                         // [N,64]
    float* h1  = (float*)d_ws + (size_t)N_NODES * 64;  // [N,64]
    float* outp = (float*)d_out;                       // [N,32]

    const size_t agg_bytes = (size_t)N_NODES * 64 * sizeof(float);

    // ---- conv1 ----
    hipMemsetAsync(agg, 0, agg_bytes, stream);
    hipLaunchKernelGGL(gine_edge, dim3(2048), dim3(256), 0, stream,
                       x, ea, srcp, dstp, c1lw, c1lb, agg);
    hipLaunchKernelGGL(gine_node, dim3(1024), dim3(256), 0, stream,
                       x, agg, c1w1, c1b1, c1w2, c1b2, h1);

    // ---- conv2 + head ----
    hipMemsetAsync(agg, 0, agg_bytes, stream);
    hipLaunchKernelGGL(gine_edge, dim3(2048), dim3(256), 0, stream,
                       h1, ea, srcp, dstp, c2lw, c2lb, agg);
    hipLaunchKernelGGL(gine_node_head, dim3(1024), dim3(256), 0, stream,
                       h1, agg, c2w1, c2b1, c2w2, c2b2, hw, hb, outp);
}

// Round 2
// 588.132 us; speedup vs baseline: 1.0008x; 1.0008x over previous
//
#include <hip/hip_runtime.h>

#define N_NODES 50000
#define N_EDGES 800000

typedef __bf16 bf16x8 __attribute__((ext_vector_type(8)));
typedef unsigned short ushort8 __attribute__((ext_vector_type(8)));
typedef float f32x4 __attribute__((ext_vector_type(4)));

__device__ __forceinline__ float lane_bcast(float v, int l) {
    return __builtin_bit_cast(float, __builtin_amdgcn_readlane(__builtin_bit_cast(int, v), l));
}

// fp32 -> bf16 bits, round-to-nearest-even
__device__ __forceinline__ unsigned short f2bf(float f) {
    unsigned u = __builtin_bit_cast(unsigned, f);
    u += 0x7fffu + ((u >> 16) & 1u);
    return (unsigned short)(u >> 16);
}

// ---------------------------------------------------------------------------
// Edge kernel (MFMA): one wave processes 16 edges.
//   msg[16,64] = relu(x[src] + ea[16,32] @ W[32,64] + b)   then atomicAdd.
// mfma_f32_16x16x32_bf16: A[m=lane&15][k=(lane>>4)*8+j],
//                         B[k=(lane>>4)*8+j][n=lane&15],
//                         D col=lane&15, row=(lane>>4)*4+reg.
// 4 MFMAs per tile (N=64 in 4 chunks of 16). Only ea/W are bf16; x, bias,
// accumulation stay fp32.
// ---------------------------------------------------------------------------
__global__ __launch_bounds__(256) void gine_edge_mfma(
    const float* __restrict__ xin,   // [N,64]
    const float* __restrict__ ea,    // [E,32]
    const int*   __restrict__ srcp,  // [E]
    const int*   __restrict__ dstp,  // [E]
    const float* __restrict__ linW,  // [32,64]
    const float* __restrict__ linB,  // [64]
    float*       __restrict__ agg)   // [N,64]
{
    const int lane   = threadIdx.x & 63;
    const int gwave  = (blockIdx.x * blockDim.x + threadIdx.x) >> 6;
    const int nwaves = (gridDim.x * blockDim.x) >> 6;
    const int row    = lane & 15;   // A: edge row / B,D: channel-within-tile
    const int quad   = lane >> 4;   // 0..3

    // B fragments: wf[t][j] = W[quad*8+j][t*16+row], bf16
    bf16x8 wf[4];
#pragma unroll
    for (int t = 0; t < 4; ++t) {
        ushort8 us;
#pragma unroll
        for (int j = 0; j < 8; ++j)
            us[j] = f2bf(linW[(quad * 8 + j) * 64 + t * 16 + row]);
        wf[t] = __builtin_bit_cast(bf16x8, us);
    }
    float bias[4];
#pragma unroll
    for (int t = 0; t < 4; ++t) bias[t] = linB[t * 16 + row];

    const int ntiles = N_EDGES / 16;   // 50000, exact
    for (int tile = gwave; tile < ntiles; tile += nwaves) {
        const int e0 = tile * 16;

        // A fragment: ea[(e0+row)*32 + quad*8 + j], j=0..7
        const float* ap = ea + (size_t)(e0 + row) * 32 + quad * 8;
        const float4 a0 = *(const float4*)ap;
        const float4 a1 = *(const float4*)(ap + 4);
        ushort8 ua;
        ua[0] = f2bf(a0.x); ua[1] = f2bf(a0.y); ua[2] = f2bf(a0.z); ua[3] = f2bf(a0.w);
        ua[4] = f2bf(a1.x); ua[5] = f2bf(a1.y); ua[6] = f2bf(a1.z); ua[7] = f2bf(a1.w);
        const bf16x8 af = __builtin_bit_cast(bf16x8, ua);

        f32x4 acc[4];
#pragma unroll
        for (int t = 0; t < 4; ++t)
            acc[t] = __builtin_amdgcn_mfma_f32_16x16x32_bf16(
                af, wf[t], (f32x4){0.f, 0.f, 0.f, 0.f}, 0, 0, 0);

        // Epilogue: reg r covers edge m = quad*4 + r, channel c = t*16 + row.
#pragma unroll
        for (int r = 0; r < 4; ++r) {
            const int e = e0 + quad * 4 + r;
            const int s = srcp[e];
            const int d = dstp[e];
            const float* xrow = xin + (size_t)s * 64;
            float*       arow = agg + (size_t)d * 64;
#pragma unroll
            for (int t = 0; t < 4; ++t) {
                const int c = t * 16 + row;
                const float v = fmaxf(xrow[c] + bias[t] + acc[t][r], 0.0f);
                atomicAdd(&arow[c], v);
            }
        }
    }
}

// ---------------------------------------------------------------------------
// Node kernel (conv1): h = x + agg; h = relu(h@w1+b1); h = relu(h@w2+b2).
// One node per wave; lane = channel. Weight columns in VGPRs.
// ---------------------------------------------------------------------------
__global__ __launch_bounds__(256) void gine_node(
    const float* __restrict__ xin,   // [N,64]
    const float* __restrict__ agg,   // [N,64]
    const float* __restrict__ w1,    // [64,64]
    const float* __restrict__ b1,    // [64]
    const float* __restrict__ w2,    // [64,64]
    const float* __restrict__ b2,    // [64]
    float*       __restrict__ hout)  // [N,64]
{
    const int lane   = threadIdx.x & 63;
    const int gwave  = (blockIdx.x * blockDim.x + threadIdx.x) >> 6;
    const int nwaves = (gridDim.x * blockDim.x) >> 6;

    float w1c[64], w2c[64];
#pragma unroll
    for (int k = 0; k < 64; ++k) w1c[k] = w1[k * 64 + lane];
#pragma unroll
    for (int k = 0; k < 64; ++k) w2c[k] = w2[k * 64 + lane];
    const float bb1 = b1[lane], bb2 = b2[lane];

    for (int n = gwave; n < N_NODES; n += nwaves) {
        const float h = xin[n * 64 + lane] + agg[n * 64 + lane];

        float t0 = bb1, t1 = 0.f, t2 = 0.f, t3 = 0.f;
#pragma unroll
        for (int k = 0; k < 64; k += 4) {
            t0 = fmaf(lane_bcast(h, k + 0), w1c[k + 0], t0);
            t1 = fmaf(lane_bcast(h, k + 1), w1c[k + 1], t1);
            t2 = fmaf(lane_bcast(h, k + 2), w1c[k + 2], t2);
            t3 = fmaf(lane_bcast(h, k + 3), w1c[k + 3], t3);
        }
        const float t = fmaxf((t0 + t1) + (t2 + t3), 0.0f);

        float u0 = bb2, u1 = 0.f, u2 = 0.f, u3 = 0.f;
#pragma unroll
        for (int k = 0; k < 64; k += 4) {
            u0 = fmaf(lane_bcast(t, k + 0), w2c[k + 0], u0);
            u1 = fmaf(lane_bcast(t, k + 1), w2c[k + 1], u1);
            u2 = fmaf(lane_bcast(t, k + 2), w2c[k + 2], u2);
            u3 = fmaf(lane_bcast(t, k + 3), w2c[k + 3], u3);
        }
        const float u = fmaxf((u0 + u1) + (u2 + u3), 0.0f);

        hout[n * 64 + lane] = u;
    }
}

// ---------------------------------------------------------------------------
// Node kernel (conv2 + head): h2 = MLP(h1 + agg); out = h2@head_w + head_b.
// ---------------------------------------------------------------------------
__global__ __launch_bounds__(256) void gine_node_head(
    const float* __restrict__ xin,   // [N,64]  (h1)
    const float* __restrict__ agg,   // [N,64]
    const float* __restrict__ w1,    // [64,64]
    const float* __restrict__ b1,    // [64]
    const float* __restrict__ w2,    // [64,64]
    const float* __restrict__ b2,    // [64]
    const float* __restrict__ hw,    // [64,32]
    const float* __restrict__ hb,    // [32]
    float*       __restrict__ outp)  // [N,32]
{
    const int lane   = threadIdx.x & 63;
    const int gwave  = (blockIdx.x * blockDim.x + threadIdx.x) >> 6;
    const int nwaves = (gridDim.x * blockDim.x) >> 6;

    float w1c[64], w2c[64], hwc[64];
#pragma unroll
    for (int k = 0; k < 64; ++k) w1c[k] = w1[k * 64 + lane];
#pragma unroll
    for (int k = 0; k < 64; ++k) w2c[k] = w2[k * 64 + lane];
#pragma unroll
    for (int k = 0; k < 64; ++k) hwc[k] = hw[k * 32 + (lane & 31)];
    const float bb1 = b1[lane], bb2 = b2[lane];
    const float hbb = hb[lane & 31];

    for (int n = gwave; n < N_NODES; n += nwaves) {
        const float h = xin[n * 64 + lane] + agg[n * 64 + lane];

        float t0 = bb1, t1 = 0.f, t2 = 0.f, t3 = 0.f;
#pragma unroll
        for (int k = 0; k < 64; k += 4) {
            t0 = fmaf(lane_bcast(h, k + 0), w1c[k + 0], t0);
            t1 = fmaf(lane_bcast(h, k + 1), w1c[k + 1], t1);
            t2 = fmaf(lane_bcast(h, k + 2), w1c[k + 2], t2);
            t3 = fmaf(lane_bcast(h, k + 3), w1c[k + 3], t3);
        }
        const float t = fmaxf((t0 + t1) + (t2 + t3), 0.0f);

        float u0 = bb2, u1 = 0.f, u2 = 0.f, u3 = 0.f;
#pragma unroll
        for (int k = 0; k < 64; k += 4) {
            u0 = fmaf(lane_bcast(t, k + 0), w2c[k + 0], u0);
            u1 = fmaf(lane_bcast(t, k + 1), w2c[k + 1], u1);
            u2 = fmaf(lane_bcast(t, k + 2), w2c[k + 2], u2);
            u3 = fmaf(lane_bcast(t, k + 3), w2c[k + 3], u3);
        }
        const float u = fmaxf((u0 + u1) + (u2 + u3), 0.0f);

        float o0 = hbb, o1 = 0.f, o2 = 0.f, o3 = 0.f;
#pragma unroll
        for (int k = 0; k < 64; k += 4) {
            o0 = fmaf(lane_bcast(u, k + 0), hwc[k + 0], o0);
            o1 = fmaf(lane_bcast(u, k + 1), hwc[k + 1], o1);
            o2 = fmaf(lane_bcast(u, k + 2), hwc[k + 2], o2);
            o3 = fmaf(lane_bcast(u, k + 3), hwc[k + 3], o3);
        }
        if (lane < 32) outp[n * 32 + lane] = (o0 + o1) + (o2 + o3);
    }
}

extern "C" void kernel_launch(void* const* d_in, const int* in_sizes, int n_in,
                              void* d_out, int out_size, void* d_ws, size_t ws_size,
                              hipStream_t stream) {
    const float* x     = (const float*)d_in[0];
    const float* ea    = (const float*)d_in[1];
    const int*   ei    = (const int*)  d_in[2];
    const float* c1lw  = (const float*)d_in[3];
    const float* c1lb  = (const float*)d_in[4];
    const float* c1w1  = (const float*)d_in[5];
    const float* c1b1  = (const float*)d_in[6];
    const float* c1w2  = (const float*)d_in[7];
    const float* c1b2  = (const float*)d_in[8];
    const float* c2lw  = (const float*)d_in[9];
    const float* c2lb  = (const float*)d_in[10];
    const float* c2w1  = (const float*)d_in[11];
    const float* c2b1  = (const float*)d_in[12];
    const float* c2w2  = (const float*)d_in[13];
    const float* c2b2  = (const float*)d_in[14];
    const float* hw    = (const float*)d_in[15];
    const float* hb    = (const float*)d_in[16];

    const int* srcp = ei;
    const int* dstp = ei + N_EDGES;

    float* agg  = (float*)d_ws;                         // [N,64]
    float* h1   = (float*)d_ws + (size_t)N_NODES * 64;  // [N,64]
    float* outp = (float*)d_out;                        // [N,32]

    const size_t agg_bytes = (size_t)N_NODES * 64 * sizeof(float);

    // ---- conv1 ----
    hipMemsetAsync(agg, 0, agg_bytes, stream);
    hipLaunchKernelGGL(gine_edge_mfma, dim3(2048), dim3(256), 0, stream,
                       x, ea, srcp, dstp, c1lw, c1lb, agg);
    hipLaunchKernelGGL(gine_node, dim3(1024), dim3(256), 0, stream,
                       x, agg, c1w1, c1b1, c1w2, c1b2, h1);

    // ---- conv2 + head ----
    hipMemsetAsync(agg, 0, agg_bytes, stream);
    hipLaunchKernelGGL(gine_edge_mfma, dim3(2048), dim3(256), 0, stream,
                       h1, ea, srcp, dstp, c2lw, c2lb, agg);
    hipLaunchKernelGGL(gine_node_head, dim3(1024), dim3(256), 0, stream,
                       h1, agg, c2w1, c2b1, c2w2, c2b2, hw, hb, outp);
}